// Round 11
// baseline (1031.151 us; speedup 1.0000x reference)
//
#include <hip/hip_runtime.h>

#define NN 16777216   // 4*256*64*256
#define CC 256
#define FF 64
#define TT 256

typedef short v8s __attribute__((ext_vector_type(8)));
typedef float v4f __attribute__((ext_vector_type(4)));

__device__ __forceinline__ unsigned short f2bf(float f) {
  unsigned u = __float_as_uint(f);
  u += 0x7fff + ((u >> 16) & 1);
  return (unsigned short)(u >> 16);
}
__device__ __forceinline__ float bf2f(unsigned short h) {
  return __uint_as_float(((unsigned)h) << 16);
}
__device__ __forceinline__ unsigned packbf2(float a, float b) {
  return (unsigned)f2bf(a) | ((unsigned)f2bf(b) << 16);
}
__device__ __forceinline__ void unpack8(uint4 u, float* d) {
  d[0] = __uint_as_float(u.x << 16); d[1] = __uint_as_float(u.x & 0xffff0000u);
  d[2] = __uint_as_float(u.y << 16); d[3] = __uint_as_float(u.y & 0xffff0000u);
  d[4] = __uint_as_float(u.z << 16); d[5] = __uint_as_float(u.z & 0xffff0000u);
  d[6] = __uint_as_float(u.w << 16); d[7] = __uint_as_float(u.w & 0xffff0000u);
}

// ---------------- helpers ----------------
__device__ __forceinline__ void blockReduce2(float& a, float& b, float* sbuf) {
  #pragma unroll
  for (int off = 32; off > 0; off >>= 1) {
    a += __shfl_down(a, off, 64);
    b += __shfl_down(b, off, 64);
  }
  int w = threadIdx.x >> 6;
  if ((threadIdx.x & 63) == 0) { sbuf[w] = a; sbuf[4 + w] = b; }
  __syncthreads();
  if (threadIdx.x == 0) {
    a = sbuf[0] + sbuf[1] + sbuf[2] + sbuf[3];
    b = sbuf[4] + sbuf[5] + sbuf[6] + sbuf[7];
  }
}

// ---------------- combined weight prep + stats/qsum zero (one dispatch) ----------------
__global__ void prep_all_k(const float* __restrict__ c1w, const float* __restrict__ c2w,
    const float* __restrict__ q2w, const float* __restrict__ o2w, const float* __restrict__ q3w,
    const float* __restrict__ lqw, const float* __restrict__ low,
    unsigned short* __restrict__ WB1, unsigned short* __restrict__ WB2,
    unsigned short* __restrict__ Q2T, unsigned short* __restrict__ O2T,
    unsigned short* __restrict__ Q3T, unsigned short* __restrict__ LQT,
    unsigned short* __restrict__ LOT, float* __restrict__ stats,
    float* __restrict__ qsum) {
  long s = (long)blockIdx.x * 256 + threadIdx.x;
  if (s < 1024) { stats[s] = 0.f; return; }
  s -= 1024;
  if (s < 589824) {
    int co = (int)(s / 2304), r = (int)(s % 2304);
    int ci = r / 9, tap = r % 9;
    WB1[(tap * 256 + co) * 256 + ci] = f2bf(c1w[s]);
    return;
  }
  s -= 589824;
  if (s < 589824) {
    int co = (int)(s / 2304), r = (int)(s % 2304);
    int ci = r / 9, tap = r % 9;
    WB2[(tap * 256 + co) * 256 + ci] = f2bf(c2w[s]);
    return;
  }
  s -= 589824;
  if (s < 196608) { int k = (int)(s / 768), n = (int)(s % 768); Q2T[n * 256 + k] = f2bf(q2w[s]); return; }
  s -= 196608;
  if (s < 65536)  { int k = (int)(s / 256), n = (int)(s % 256); O2T[n * 256 + k] = f2bf(o2w[s]); return; }
  s -= 65536;
  if (s < 196608) { int k = (int)(s / 768), n = (int)(s % 768); Q3T[n * 256 + k] = f2bf(q3w[s]); return; }
  s -= 196608;
  if (s < 196608) { int k = (int)(s / 768), n = (int)(s % 768); LQT[n * 256 + k] = f2bf(lqw[s]); return; }
  s -= 196608;
  if (s < 65536)  { int k = (int)(s / 256), n = (int)(s % 256); LOT[n * 256 + k] = f2bf(low[s]); return; }
  s -= 65536;
  if (s < 65536)  { qsum[s] = 0.f; }
}

// ---------------- GroupNorm stats (NCHW contiguous: 131072/group) ----------------
__global__ __launch_bounds__(256) void gn_stats_contig(const float* __restrict__ src, float* __restrict__ stats) {
  __shared__ float sbuf[8];
  int grp = blockIdx.x >> 3, chunk = blockIdx.x & 7;
  const float4* p = (const float4*)src + grp * 32768 + chunk * 4096;
  float s = 0.f, ss = 0.f;
  for (int i = threadIdx.x; i < 4096; i += 256) {
    float4 v = p[i];
    s += v.x + v.y + v.z + v.w;
    ss += v.x * v.x + v.y * v.y + v.z * v.z + v.w * v.w;
  }
  blockReduce2(s, ss, sbuf);
  if (threadIdx.x == 0) { atomicAdd(&stats[grp], s); atomicAdd(&stats[128 + grp], ss); }
}

// GN apply + transpose to bf16 [b][f][t][ci]
__global__ __launch_bounds__(256) void gn_apply_tr_k(const float* __restrict__ src,
    const float* __restrict__ stats, unsigned short* __restrict__ XC, float eps) {
  __shared__ float sT[32][33];
  int bx = blockIdx.x;
  int r = bx >> 6;
  int c0 = ((bx >> 3) & 7) * 32;
  int t0 = (bx & 7) * 32;
  int b = r >> 6, f = r & 63;
  int tl = threadIdx.x & 31, tr = threadIdx.x >> 5;
  #pragma unroll
  for (int i = 0; i < 4; ++i) {
    int c = c0 + tr + i * 8;
    int grp = b * 32 + (c >> 3);
    float mean = stats[grp] * (1.f / 131072.f);
    float var = stats[128 + grp] * (1.f / 131072.f) - mean * mean;
    float rv = rsqrtf(var + eps);
    float v = src[((b * 256 + c) * 64 + f) * 256 + t0 + tl];
    sT[tr + i * 8][tl] = (v - mean) * rv;
  }
  __syncthreads();
  #pragma unroll
  for (int i = 0; i < 4; ++i) {
    int t = t0 + tr + i * 8;
    XC[(((size_t)(b * 64 + f)) * 256 + t) * 256 + c0 + tl] = f2bf(sT[tl][tr + i * 8]);
  }
}

// GN apply + gated residual + transpose to XF fp32 [(b*256+t)*64+f][c]
__global__ __launch_bounds__(256) void gn_tr_resid_k(const float* __restrict__ h,
    const float* __restrict__ x, const float* __restrict__ stats,
    const float* __restrict__ gate, float* __restrict__ XF, float eps) {
  __shared__ float sT[32][33];
  int bx = blockIdx.x;
  int r = bx >> 6;
  int c0 = ((bx >> 3) & 7) * 32;
  int t0 = (bx & 7) * 32;
  int b = r >> 6, f = r & 63;
  int tl = threadIdx.x & 31, tr = threadIdx.x >> 5;
  float g = gate[0];
  #pragma unroll
  for (int i = 0; i < 4; ++i) {
    int c = c0 + tr + i * 8;
    int grp = b * 32 + (c >> 3);
    float mean = stats[grp] * (1.f / 131072.f);
    float var = stats[128 + grp] * (1.f / 131072.f) - mean * mean;
    float rv = rsqrtf(var + eps);
    int idx = ((b * 256 + c) * 64 + f) * 256 + t0 + tl;
    sT[tr + i * 8][tl] = x[idx] + g * (h[idx] - mean) * rv;
  }
  __syncthreads();
  #pragma unroll
  for (int i = 0; i < 4; ++i) {
    int t = t0 + tr + i * 8;
    XF[(((size_t)(b * 256 + t)) * 64 + f) * 256 + c0 + tl] = sT[tl][tr + i * 8];
  }
}

// ---------------- conv 3x3 via MFMA; fused output GN-stats ----------------
// XC bf16 [b][f][t][ci]; wb bf16 [tap][co][ci]; out fp32 [b][co][f][t].
// co split 4-ways (64 co/block): grid (64,16)=1024 blocks -> 4 blocks/CU.
__global__ __launch_bounds__(256, 4) void conv3x3_mfma_k(const unsigned short* __restrict__ XC,
    const unsigned short* __restrict__ wb, const float* __restrict__ bias,
    const float* __restrict__ temb, const float* __restrict__ gd,
    float* __restrict__ out, float* __restrict__ ostats, int mode) {
  __shared__ __align__(16) unsigned short sIn[258][40];
  __shared__ __align__(16) unsigned short sW[3][64][40];
  int f  = blockIdx.x;
  int b  = blockIdx.y >> 2;
  int co0 = (blockIdx.y & 3) * 64;
  int tid = threadIdx.x;
  int wave = tid >> 6, lane = tid & 63;
  int lm = lane & 15, quad = lane >> 4;
  int w64 = wave * 64;
  v4f acc[4][4];
  #pragma unroll
  for (int i = 0; i < 4; ++i)
    #pragma unroll
    for (int j = 0; j < 4; ++j) acc[i][j] = (v4f)(0.f);

  for (int ci0 = 0; ci0 < 256; ci0 += 32) {
    for (int df = 0; df < 3; ++df) {
      __syncthreads();
      // stage one input f-row (258 t x 32 ci)
      for (int s = tid; s < 1032; s += 256) {
        int tl = s >> 2, part = s & 3;
        int fi = f + df - 1, tg = tl - 1;
        uint4 val = make_uint4(0, 0, 0, 0);
        if (fi >= 0 && fi < 64 && tg >= 0 && tg < 256)
          val = *(const uint4*)&XC[(((size_t)(b * 64 + fi)) * 256 + tg) * 256 + ci0 + part * 8];
        *(uint4*)&sIn[tl][part * 8] = val;
      }
      // stage 3 taps of weights (64 co x 32 ci each)
      for (int s = tid; s < 768; s += 256) {
        int tap3 = s >> 8, r = s & 255;
        int co = r >> 2, part = r & 3;
        *(uint4*)&sW[tap3][co][part * 8] =
            *(const uint4*)&wb[((size_t)((df * 3 + tap3) * 256) + co0 + co) * 256 + ci0 + part * 8];
      }
      __syncthreads();
      #pragma unroll
      for (int dt = 0; dt < 3; ++dt) {
        v8s A[4];
        #pragma unroll
        for (int mt = 0; mt < 4; ++mt)
          A[mt] = *(const v8s*)&sIn[w64 + mt * 16 + lm + dt][quad * 8];
        #pragma unroll
        for (int nt = 0; nt < 4; ++nt) {
          v8s B = *(const v8s*)&sW[dt][nt * 16 + lm][quad * 8];
          #pragma unroll
          for (int mt = 0; mt < 4; ++mt)
            acc[mt][nt] = __builtin_amdgcn_mfma_f32_16x16x32_bf16(A[mt], B, acc[mt][nt], 0, 0, 0);
        }
      }
    }
  }
  __syncthreads();   // done reading sIn/sW; reuse sIn as float scratch
  float* sStat = (float*)sIn;     // [wave][nt][lm][2] = 512 floats
  float gdv = mode ? gd[0] : 0.f;
  float sch, qch;
  #pragma unroll
  for (int nt = 0; nt < 4; ++nt) {
    int co = co0 + nt * 16 + lm;
    float bb = 0.f;
    if (mode) bb = bias[co] + gdv * temb[b * 256 + co];
    sch = 0.f; qch = 0.f;
    #pragma unroll
    for (int mt = 0; mt < 4; ++mt) {
      int t = w64 + mt * 16 + quad * 4;
      float v0 = acc[mt][nt][0] + bb, v1 = acc[mt][nt][1] + bb;
      float v2 = acc[mt][nt][2] + bb, v3 = acc[mt][nt][3] + bb;
      if (mode) {
        v0 = v0 / (1.f + expf(-v0)); v1 = v1 / (1.f + expf(-v1));
        v2 = v2 / (1.f + expf(-v2)); v3 = v3 / (1.f + expf(-v3));
      }
      float4 o; o.x = v0; o.y = v1; o.z = v2; o.w = v3;
      *(float4*)&out[(((size_t)b * 256 + co) * 64 + f) * 256 + t] = o;
      sch += v0 + v1 + v2 + v3;
      qch += v0 * v0 + v1 * v1 + v2 * v2 + v3 * v3;
    }
    // reduce across quads (same channel, different t)
    sch += __shfl_xor(sch, 16); qch += __shfl_xor(qch, 16);
    sch += __shfl_xor(sch, 32); qch += __shfl_xor(qch, 32);
    if (quad == 0) {
      sStat[((wave * 4 + nt) * 16 + lm) * 2]     = sch;
      sStat[((wave * 4 + nt) * 16 + lm) * 2 + 1] = qch;
    }
  }
  __syncthreads();
  if (tid < 64) {
    int c = tid;                     // channel within block = nt*16+lm
    int nt = c >> 4, lmm = c & 15;
    float s = 0.f, q = 0.f;
    #pragma unroll
    for (int w = 0; w < 4; ++w) {
      s += sStat[((w * 4 + nt) * 16 + lmm) * 2];
      q += sStat[((w * 4 + nt) * 16 + lmm) * 2 + 1];
    }
    s += __shfl_xor(s, 1); q += __shfl_xor(q, 1);
    s += __shfl_xor(s, 2); q += __shfl_xor(q, 2);
    s += __shfl_xor(s, 4); q += __shfl_xor(q, 4);
    if ((c & 7) == 0) {
      int g = (co0 + c) >> 3;
      atomicAdd(&ostats[b * 32 + g], s);
      atomicAdd(&ostats[128 + b * 32 + g], q);
    }
  }
}

// ---------------- MFMA GEMM: Cb bf16 [M,N] = gn?(A fp32 [M,256]) @ B (+bias) ----------------
// 128-wide N tile (acc[4][4]): proven form (wider blows unified VGPR/AGPR, r9).
// qsum mode (layer3): q-cols (n0<256) are NOT written; instead per-column sums
// over the block's 128 rows (all one (b,f) seq) accumulate into qsum[bfl][col]
// for attn3's pooled query. 4 atomics/address total — cheap.
__global__ __launch_bounds__(256) void gemm_af32_k(const float* __restrict__ A, int lda,
    const unsigned short* __restrict__ BT, const float* __restrict__ bias,
    unsigned short* __restrict__ Cb, int ldc,
    const float* __restrict__ gstats, int growbase, float eps,
    float* __restrict__ qsum, int qrowbase) {
  __shared__ __align__(16) unsigned short sA[128][40];
  __shared__ __align__(16) unsigned short sB[128][40];
  int n0 = blockIdx.x * 128, m0 = blockIdx.y * 128;
  int tid = threadIdx.x;
  int wave = tid >> 6, lane = tid & 63;
  int wm = wave >> 1, wn = wave & 1;
  int lm = lane & 15, quad = lane >> 4;
  v4f acc[4][4];
  #pragma unroll
  for (int i = 0; i < 4; ++i)
    #pragma unroll
    for (int j = 0; j < 4; ++j) acc[i][j] = (v4f)(0.f);

  for (int k0 = 0; k0 < 256; k0 += 32) {
    __syncthreads();
    #pragma unroll
    for (int i = 0; i < 4; ++i) {
      int s = tid + i * 256;
      int row = s >> 3, k4 = s & 7;
      float4 av = *(const float4*)&A[(size_t)(m0 + row) * lda + k0 + k4 * 4];
      if (gstats) {
        int grp = ((growbase + m0 + row) >> 14) * 32 + ((k0 + k4 * 4) >> 3);
        float mean = gstats[grp] * (1.f / 131072.f);
        float var = gstats[128 + grp] * (1.f / 131072.f) - mean * mean;
        float rr = rsqrtf(var + eps);
        av.x = (av.x - mean) * rr; av.y = (av.y - mean) * rr;
        av.z = (av.z - mean) * rr; av.w = (av.w - mean) * rr;
      }
      *(uint2*)&sA[row][k4 * 4] = make_uint2(packbf2(av.x, av.y), packbf2(av.z, av.w));
    }
    #pragma unroll
    for (int i = 0; i < 2; ++i) {
      int s = tid + i * 256;
      int n = s >> 2, part = s & 3;
      *(uint4*)&sB[n][part * 8] = *(const uint4*)&BT[(size_t)(n0 + n) * 256 + k0 + part * 8];
    }
    __syncthreads();
    v8s Af[4];
    #pragma unroll
    for (int mt = 0; mt < 4; ++mt)
      Af[mt] = *(const v8s*)&sA[wm * 64 + mt * 16 + lm][quad * 8];
    #pragma unroll
    for (int nt = 0; nt < 4; ++nt) {
      v8s Bf = *(const v8s*)&sB[wn * 64 + nt * 16 + lm][quad * 8];
      #pragma unroll
      for (int mt = 0; mt < 4; ++mt)
        acc[mt][nt] = __builtin_amdgcn_mfma_f32_16x16x32_bf16(Af[mt], Bf, acc[mt][nt], 0, 0, 0);
    }
  }
  if (qsum && n0 < 256) {
    // column sums over this wave's wm-half (64 rows); both wm waves atomic
    #pragma unroll
    for (int nt = 0; nt < 4; ++nt) {
      int col = n0 + wn * 64 + nt * 16 + lm;
      float bb = bias ? bias[col] : 0.f;
      float cs = 0.f;
      #pragma unroll
      for (int mt = 0; mt < 4; ++mt)
        #pragma unroll
        for (int r = 0; r < 4; ++r)
          cs += acc[mt][nt][r] + bb;
      cs += __shfl_xor(cs, 16);
      cs += __shfl_xor(cs, 32);
      if (quad == 0) {
        int qrow = (qrowbase + m0) >> 8;
        atomicAdd(&qsum[(size_t)qrow * 256 + col], cs);
      }
    }
  } else {
    #pragma unroll
    for (int nt = 0; nt < 4; ++nt) {
      int col = n0 + wn * 64 + nt * 16 + lm;
      float bb = bias ? bias[col] : 0.f;
      #pragma unroll
      for (int mt = 0; mt < 4; ++mt) {
        int row = m0 + wm * 64 + mt * 16 + quad * 4;
        #pragma unroll
        for (int r = 0; r < 4; ++r)
          Cb[(size_t)(row + r) * ldc + col] = f2bf(acc[mt][nt][r] + bb);
      }
    }
  }
}

// ---------------- MFMA GEMM, A bf16 ----------------
// mode 0: plain bf16 Cb out.
// mode 1: fused rowGN + gate + residual-add, written TRANSPOSED into xt layout.
// mode 2: LSA direct-out: writes final out[((b*256+col)*64+f)*256+t].
__global__ __launch_bounds__(256) void gemm_abf16_k(const unsigned short* __restrict__ A, int lda,
    const unsigned short* __restrict__ BT,
    const float* __restrict__ xfin, float* __restrict__ xtout, int rowbase,
    unsigned short* __restrict__ Cb, int ldc, const float* __restrict__ gate, int mode) {
  __shared__ __align__(16) unsigned short sA[128][40];
  __shared__ __align__(16) unsigned short sB[128][40];
  int n0 = blockIdx.x * 128, m0 = blockIdx.y * 128;
  int tid = threadIdx.x;
  int wave = tid >> 6, lane = tid & 63;
  int wm = wave >> 1, wn = wave & 1;
  int lm = lane & 15, quad = lane >> 4;
  v4f acc[4][4];
  #pragma unroll
  for (int i = 0; i < 4; ++i)
    #pragma unroll
    for (int j = 0; j < 4; ++j) acc[i][j] = (v4f)(0.f);

  for (int k0 = 0; k0 < 256; k0 += 32) {
    __syncthreads();
    #pragma unroll
    for (int i = 0; i < 2; ++i) {
      int s = tid + i * 256;
      int row = s >> 2, part = s & 3;
      *(uint4*)&sA[row][part * 8] = *(const uint4*)&A[(size_t)(m0 + row) * lda + k0 + part * 8];
      *(uint4*)&sB[row][part * 8] = *(const uint4*)&BT[(size_t)(n0 + row) * 256 + k0 + part * 8];
    }
    __syncthreads();
    v8s Af[4];
    #pragma unroll
    for (int mt = 0; mt < 4; ++mt)
      Af[mt] = *(const v8s*)&sA[wm * 64 + mt * 16 + lm][quad * 8];
    #pragma unroll
    for (int nt = 0; nt < 4; ++nt) {
      v8s Bf = *(const v8s*)&sB[wn * 64 + nt * 16 + lm][quad * 8];
      #pragma unroll
      for (int mt = 0; mt < 4; ++mt)
        acc[mt][nt] = __builtin_amdgcn_mfma_f32_16x16x32_bf16(Af[mt], Bf, acc[mt][nt], 0, 0, 0);
    }
  }
  if (mode == 1) {
    float g = gate[0];
    #pragma unroll
    for (int mt = 0; mt < 4; ++mt) {
      int rowb = m0 + wm * 64 + mt * 16 + quad * 4;
      #pragma unroll
      for (int r = 0; r < 4; ++r) {
        int rowl = rowb + r;
        int rowg = rowbase + rowl;
        int b = rowg >> 14, t = (rowg >> 6) & 255, fq = rowg & 63;
        size_t xtrow = (size_t)((b * 64 + fq) * 256 + t) * 256;
        #pragma unroll
        for (int nt = 0; nt < 4; ++nt) {
          float v = acc[mt][nt][r];
          float s = v, q = v * v;
          s += __shfl_xor(s, 1); q += __shfl_xor(q, 1);
          s += __shfl_xor(s, 2); q += __shfl_xor(q, 2);
          s += __shfl_xor(s, 4); q += __shfl_xor(q, 4);
          float m = s * 0.125f;
          float var = q * 0.125f - m * m;
          float norm = (v - m) * rsqrtf(var + 1e-5f);
          int col = n0 + wn * 64 + nt * 16 + lm;
          xtout[xtrow + col] = xfin[(size_t)rowl * 256 + col] + g * norm;
        }
      }
    }
  } else if (mode == 2) {
    #pragma unroll
    for (int mt = 0; mt < 4; ++mt) {
      int rowb = m0 + wm * 64 + mt * 16 + quad * 4;
      #pragma unroll
      for (int r = 0; r < 4; ++r) {
        int rowl = rowb + r;
        int rowg = rowbase + rowl;
        int b = rowg >> 14, fq = (rowg >> 8) & 63, t = rowg & 255;
        #pragma unroll
        for (int nt = 0; nt < 4; ++nt) {
          int col = n0 + wn * 64 + nt * 16 + lm;
          float v = acc[mt][nt][r] + xfin[(size_t)rowl * 256 + col];
          xtout[(((size_t)b * 256 + col) * 64 + fq) * 256 + t] = v;
        }
      }
    }
  } else {
    #pragma unroll
    for (int nt = 0; nt < 4; ++nt) {
      int col = n0 + wn * 64 + nt * 16 + lm;
      #pragma unroll
      for (int mt = 0; mt < 4; ++mt) {
        int row = m0 + wm * 64 + mt * 16 + quad * 4;
        #pragma unroll
        for (int r = 0; r < 4; ++r)
          Cb[(size_t)(row + r) * ldc + col] = f2bf(acc[mt][nt][r]);
      }
    }
  }
}

// ---------------- fp32 GEMM (tiny out3 matmul), optional fused row-GN ----------------
__global__ __launch_bounds__(256) void gemm_k(const float* __restrict__ A, int lda,
    const float* __restrict__ Bm, int N, const float* __restrict__ bias,
    float* __restrict__ Cm, int ldc, int gn) {
  __shared__ __align__(16) float sA[16][64];
  __shared__ __align__(16) float sB[16][64];
  int n0 = blockIdx.x * 64, m0 = blockIdx.y * 64;
  int tid = threadIdx.x;
  int tx = tid & 15, ty = tid >> 4;
  int arow = m0 + (tid >> 2), acol = (tid & 3) * 4;
  int brow = tid >> 4, bcol = (tid & 15) * 4;
  float acc[4][4] = {};
  for (int k0 = 0; k0 < 256; k0 += 16) {
    __syncthreads();
    float4 av = *(const float4*)&A[(size_t)arow * lda + k0 + acol];
    sA[acol + 0][tid >> 2] = av.x;
    sA[acol + 1][tid >> 2] = av.y;
    sA[acol + 2][tid >> 2] = av.z;
    sA[acol + 3][tid >> 2] = av.w;
    *(float4*)&sB[brow][bcol] = *(const float4*)&Bm[(k0 + brow) * N + n0 + bcol];
    __syncthreads();
    #pragma unroll
    for (int kk = 0; kk < 16; ++kk) {
      float4 a = *(const float4*)&sA[kk][ty * 4];
      float4 b = *(const float4*)&sB[kk][tx * 4];
      float aa[4] = {a.x, a.y, a.z, a.w};
      float bb[4] = {b.x, b.y, b.z, b.w};
      #pragma unroll
      for (int i = 0; i < 4; ++i)
        #pragma unroll
        for (int j = 0; j < 4; ++j)
          acc[i][j] += aa[i] * bb[j];
    }
  }
  #pragma unroll
  for (int i = 0; i < 4; ++i) {
    float m = 0.f, rv = 1.f;
    if (gn) {
      float s = acc[i][0] + acc[i][1] + acc[i][2] + acc[i][3];
      float q = acc[i][0] * acc[i][0] + acc[i][1] * acc[i][1]
              + acc[i][2] * acc[i][2] + acc[i][3] * acc[i][3];
      s += __shfl_xor(s, 1); q += __shfl_xor(q, 1);
      m = s * 0.125f;
      float var = q * 0.125f - m * m;
      rv = rsqrtf(var + 1e-5f);
    }
    #pragma unroll
    for (int j = 0; j < 4; ++j) {
      int n = n0 + tx * 4 + j;
      float v = acc[i][j];
      if (gn) v = (v - m) * rv;
      else if (bias) v += bias[n];
      Cm[(size_t)(m0 + ty * 4 + i) * ldc + n] = v;
    }
  }
}

// ---------------- attention: frequency axis (seq 64) via MFMA, in-place y -> q cols ----------------
__global__ __launch_bounds__(256) void attn2_mfma_k(unsigned short* __restrict__ Q) {
  __shared__ __align__(16) unsigned short sP[4][64][72];
  __shared__ __align__(16) unsigned short sVt[4][32][72];
  int bt = blockIdx.x;
  int tid = threadIdx.x;
  int wave = tid >> 6, lane = tid & 63;
  int lm = lane & 15, quad = lane >> 4;
  const float scale = 0.17677669529663687f;
  size_t rowbase = (size_t)bt * 64;
  unsigned short (*P)[72] = sP[wave];
  unsigned short (*Vt)[72] = sVt[wave];
  #pragma unroll
  for (int hh = 0; hh < 2; ++hh) {
    int h = wave * 2 + hh;
    int hoff = h * 32;
    v8s Af[4], Bf[4];
    #pragma unroll
    for (int mt = 0; mt < 4; ++mt)
      Af[mt] = *(const v8s*)&Q[(rowbase + mt * 16 + lm) * 768 + hoff + quad * 8];
    #pragma unroll
    for (int nt = 0; nt < 4; ++nt)
      Bf[nt] = *(const v8s*)&Q[(rowbase + nt * 16 + lm) * 768 + 256 + hoff + quad * 8];
    v4f S[4][4];
    #pragma unroll
    for (int mt = 0; mt < 4; ++mt)
      #pragma unroll
      for (int nt = 0; nt < 4; ++nt)
        S[mt][nt] = __builtin_amdgcn_mfma_f32_16x16x32_bf16(Af[mt], Bf[nt], (v4f)(0.f), 0, 0, 0);
    #pragma unroll
    for (int part = 0; part < 4; ++part) {
      uint4 u = *(const uint4*)&Q[(rowbase + lane) * 768 + 512 + hoff + part * 8];
      unsigned short* up = (unsigned short*)&u;
      #pragma unroll
      for (int j = 0; j < 8; ++j) Vt[part * 8 + j][lane] = up[j];
    }
    float inv[4][4];
    #pragma unroll
    for (int mt = 0; mt < 4; ++mt) {
      #pragma unroll
      for (int r = 0; r < 4; ++r) {
        float v0 = S[mt][0][r] * scale, v1 = S[mt][1][r] * scale;
        float v2 = S[mt][2][r] * scale, v3 = S[mt][3][r] * scale;
        float mx = fmaxf(fmaxf(v0, v1), fmaxf(v2, v3));
        mx = fmaxf(mx, __shfl_xor(mx, 1));
        mx = fmaxf(mx, __shfl_xor(mx, 2));
        mx = fmaxf(mx, __shfl_xor(mx, 4));
        mx = fmaxf(mx, __shfl_xor(mx, 8));
        float e0 = __expf(v0 - mx), e1 = __expf(v1 - mx);
        float e2 = __expf(v2 - mx), e3 = __expf(v3 - mx);
        float sm = e0 + e1 + e2 + e3;
        sm += __shfl_xor(sm, 1);
        sm += __shfl_xor(sm, 2);
        sm += __shfl_xor(sm, 4);
        sm += __shfl_xor(sm, 8);
        inv[mt][r] = 1.f / sm;
        int row = mt * 16 + quad * 4 + r;
        P[row][lm]      = f2bf(e0);
        P[row][16 + lm] = f2bf(e1);
        P[row][32 + lm] = f2bf(e2);
        P[row][48 + lm] = f2bf(e3);
      }
    }
    v8s Ap[4][2], Bv[2][2];
    #pragma unroll
    for (int mt = 0; mt < 4; ++mt)
      #pragma unroll
      for (int kc = 0; kc < 2; ++kc)
        Ap[mt][kc] = *(const v8s*)&P[mt * 16 + lm][kc * 32 + quad * 8];
    #pragma unroll
    for (int nd = 0; nd < 2; ++nd)
      #pragma unroll
      for (int kc = 0; kc < 2; ++kc)
        Bv[nd][kc] = *(const v8s*)&Vt[nd * 16 + lm][kc * 32 + quad * 8];
    #pragma unroll
    for (int mt = 0; mt < 4; ++mt) {
      #pragma unroll
      for (int nd = 0; nd < 2; ++nd) {
        v4f O = (v4f)(0.f);
        O = __builtin_amdgcn_mfma_f32_16x16x32_bf16(Ap[mt][0], Bv[nd][0], O, 0, 0, 0);
        O = __builtin_amdgcn_mfma_f32_16x16x32_bf16(Ap[mt][1], Bv[nd][1], O, 0, 0, 0);
        #pragma unroll
        for (int r = 0; r < 4; ++r)
          P[mt * 16 + quad * 4 + r][nd * 16 + lm] = f2bf(O[r] * inv[mt][r]);
      }
    }
    #pragma unroll
    for (int part = 0; part < 4; ++part) {
      uint4 u = *(const uint4*)&P[lane][part * 8];
      *(uint4*)&Q[(rowbase + lane) * 768 + hoff + part * 8] = u;
    }
  }
}

// ---------------- attention: global time (pooled q from qsum, seq 256) ----------------
__global__ __launch_bounds__(256) void attn3_k(const unsigned short* __restrict__ Q3,
                                               const float* __restrict__ qsum,
                                               float* __restrict__ y3, int bf_base) {
  __shared__ float sQp[64][33];
  __shared__ float sqm[32];
  __shared__ float sp[256];
  __shared__ float sred[256];
  int bfl = blockIdx.x >> 3, h = blockIdx.x & 7;
  int tid = threadIdx.x;
  int tq = tid >> 2, c4 = tid & 3;
  int d8 = c4 * 8;
  const float scale = 0.17677669529663687f;
  size_t rowbase = (size_t)bfl * 256;
  // ---- pooled q directly from GEMM-accumulated column sums ----
  if (tid < 32)
    sqm[tid] = qsum[(size_t)(bf_base + bfl) * 256 + h * 32 + tid] * (1.f / 256.f);
  __syncthreads();
  // ---- k . qm ----
  {
    float dot = 0.f;
    #pragma unroll
    for (int p = 0; p < 4; ++p) {
      float v[8];
      unpack8(*(const uint4*)&Q3[(rowbase + tid) * 768 + 256 + h * 32 + p * 8], v);
      #pragma unroll
      for (int j = 0; j < 8; ++j) dot += sqm[p * 8 + j] * v[j];
    }
    sp[tid] = dot * scale;
    sred[tid] = sp[tid];
  }
  __syncthreads();
  for (int st = 128; st > 0; st >>= 1) { if (tid < st) sred[tid] = fmaxf(sred[tid], sred[tid + st]); __syncthreads(); }
  float mx = sred[0];
  __syncthreads();
  float e = expf(sp[tid] - mx);
  sred[tid] = e;
  __syncthreads();
  for (int st = 128; st > 0; st >>= 1) { if (tid < st) sred[tid] += sred[tid + st]; __syncthreads(); }
  float rinv = 1.f / sred[0];
  sp[tid] = e * rinv;
  __syncthreads();
  // ---- weighted V sum ----
  {
    float a[8] = {};
    #pragma unroll
    for (int i = 0; i < 4; ++i) {
      int t = i * 64 + tq;
      float w = sp[t];
      float v[8];
      unpack8(*(const uint4*)&Q3[(rowbase + t) * 768 + 512 + h * 32 + d8], v);
      #pragma unroll
      for (int j = 0; j < 8; ++j) a[j] += w * v[j];
    }
    #pragma unroll
    for (int j = 0; j < 8; ++j) sQp[tq][d8 + j] = a[j];
  }
  __syncthreads();
  if (tid < 32) {
    float o = 0.f;
    for (int g = 0; g < 64; ++g) o += sQp[g][tid];
    y3[(size_t)(bf_base + bfl) * 256 + h * 32 + tid] = o;
  }
}

// ---------------- LSA: local window 16 along T, bf16 in, o bf16 -> q cols ----------------
__global__ __launch_bounds__(256) void lsa_attn_k(unsigned short* __restrict__ Q4) {
  __shared__ __align__(16) float sX[16][772];
  __shared__ float sS[8][16][17];
  __shared__ float sInv[8][16];
  int bfl = blockIdx.x >> 4, w = blockIdx.x & 15;
  int tid = threadIdx.x;
  size_t rb = ((size_t)(bfl * 256 + w * 16)) * 768;
  for (int s = tid; s < 1536; s += 256) {
    int t = s / 96, c8 = (s - t * 96) * 8;
    unpack8(*(const uint4*)&Q4[rb + t * 768 + c8], &sX[t][c8]);
  }
  __syncthreads();
  const float scale = 0.17677669529663687f;
  #pragma unroll
  for (int rep = 0; rep < 8; ++rep) {
    int idx = tid + rep * 256;
    int h = idx >> 8, q = (idx >> 4) & 15, k = idx & 15;
    float dot = 0.f;
    const float* qp = &sX[q][h * 32];
    const float* kp = &sX[k][256 + h * 32];
    for (int d = 0; d < 32; ++d) dot += qp[d] * kp[d];
    sS[h][q][k] = dot * scale;
  }
  __syncthreads();
  if (tid < 128) {
    int h = tid >> 4, q = tid & 15;
    float mx = -1e30f;
    for (int k = 0; k < 16; ++k) mx = fmaxf(mx, sS[h][q][k]);
    float sum = 0.f;
    for (int k = 0; k < 16; ++k) { float e = expf(sS[h][q][k] - mx); sS[h][q][k] = e; sum += e; }
    sInv[h][q] = 1.f / sum;
  }
  __syncthreads();
  #pragma unroll
  for (int rep = 0; rep < 8; ++rep) {
    int idx = tid + rep * 256;
    int t = idx >> 7, c2 = (idx & 127) * 2;
    int h = c2 >> 5;
    float a0 = 0.f, a1 = 0.f;
    for (int k = 0; k < 16; ++k) {
      float p = sS[h][t][k];
      a0 += p * sX[k][512 + c2];
      a1 += p * sX[k][512 + c2 + 1];
    }
    float riv = sInv[h][t];
    *(unsigned*)&Q4[rb + t * 768 + c2] = packbf2(a0 * riv, a1 * riv);
  }
}

// ---------------- fused broadcast-add + layer4 GN stats ----------------
// block = half a (b,f) plane (contiguous 128KB). y3n operand is lane-constant.
// Stats of the POST-add value; proven gn_stats_xt2 reduction (32K atomics).
__global__ __launch_bounds__(256) void bcast_stats_k(float* __restrict__ XT, const float* __restrict__ y3n,
                                                     const float* __restrict__ gate, float* __restrict__ stats) {
  __shared__ float sacc[4][64];
  int bf = blockIdx.x >> 1, half = blockIdx.x & 1;
  int b = bf >> 6;
  int tid = threadIdx.x;
  float4* p = (float4*)XT + (size_t)bf * 16384 + (size_t)half * 8192;
  int lane = tid & 63, wave = tid >> 6;
  float4 a = ((const float4*)y3n)[(size_t)bf * 64 + lane];
  float g = gate[0];
  a.x *= g; a.y *= g; a.z *= g; a.w *= g;
  float s = 0.f, q = 0.f;
  #pragma unroll 4
  for (int k = 0; k < 32; ++k) {
    int idx = tid + k * 256;
    float4 v = p[idx];
    v.x += a.x; v.y += a.y; v.z += a.z; v.w += a.w;
    p[idx] = v;
    s += v.x + v.y + v.z + v.w;
    q += v.x * v.x + v.y * v.y + v.z * v.z + v.w * v.w;
  }
  s += __shfl_xor(s, 1); q += __shfl_xor(q, 1);
  if ((lane & 1) == 0) {
    int gg = (lane >> 1) & 31;
    sacc[wave][gg * 2] = s;
    sacc[wave][gg * 2 + 1] = q;
  }
  __syncthreads();
  if (tid < 64) {
    int gg = tid >> 1, isq = tid & 1;
    float acc = sacc[0][gg * 2 + isq] + sacc[1][gg * 2 + isq]
              + sacc[2][gg * 2 + isq] + sacc[3][gg * 2 + isq];
    atomicAdd(&stats[isq * 128 + b * 32 + gg], acc);
  }
}

// ---------------- launch ----------------
extern "C" void kernel_launch(void* const* d_in, const int* in_sizes, int n_in,
                              void* d_out, int out_size, void* d_ws, size_t ws_size,
                              hipStream_t stream) {
  (void)in_sizes; (void)n_in; (void)out_size;
  const float* x        = (const float*)d_in[0];
  const float* temb     = (const float*)d_in[1];
  const float* conv1_w  = (const float*)d_in[2];
  const float* conv1_b  = (const float*)d_in[3];
  const float* conv2_w  = (const float*)d_in[4];
  const float* g_diff   = (const float*)d_in[5];
  const float* g_res    = (const float*)d_in[6];
  const float* g2       = (const float*)d_in[7];
  const float* g3       = (const float*)d_in[8];
  const float* qkv2_w   = (const float*)d_in[9];
  const float* qkv2_b   = (const float*)d_in[10];
  const float* out2_w   = (const float*)d_in[11];
  const float* qkv3_w   = (const float*)d_in[12];
  const float* qkv3_b   = (const float*)d_in[13];
  const float* out3_w   = (const float*)d_in[14];
  const float* lsa_qkv_w = (const float*)d_in[15];
  const float* lsa_out_w = (const float*)d_in[16];
  float* out = (float*)d_out;
  float* ws = (float*)d_ws;

  int NCHv = 4;
  {
    auto need = [](int nch) -> size_t {
      size_t rows = 65536 / nch;
      size_t uslots = rows * 512;
      if (uslots < 8388608) uslots = 8388608;
      return 4ull * ((size_t)NN + uslots + 950272 + 198000);
    };
    if (ws_size >= need(1)) NCHv = 1;
    else if (ws_size >= need(2)) NCHv = 2;
  }
  const size_t rows = 65536 / NCHv;

  float* W = ws;                                  // NN fp32 trunk
  float* U = ws + (size_t)NN;                     // union region
  unsigned short* XC  = (unsigned short*)U;       // NN bf16 (conv staging)
  unsigned short* QB  = (unsigned short*)U;       // rows*768 bf16 (qkv)
  size_t uslots = rows * 512; if (uslots < 8388608) uslots = 8388608;
  float* WREG = U + uslots;
  unsigned short* WB1   = (unsigned short*)WREG;
  unsigned short* WB2   = WB1 + 589824;
  unsigned short* QKV2T = WB2 + 589824;
  unsigned short* OUT2T = QKV2T + 196608;
  unsigned short* QKV3T = OUT2T + 65536;
  unsigned short* LSAQT = QKV3T + 196608;
  unsigned short* LSAOT = LSAQT + 196608;
  float* Y3    = WREG + 950272;
  float* QSUM  = Y3 + 65536;                      // 65536 floats (was Y3O)
  float* Y3N   = QSUM + 65536;
  float* STATS = Y3N + 65536;                     // 1024 floats: ST0..ST3
  float* ST0 = STATS, *ST1 = STATS + 256, *ST2 = STATS + 512, *ST3 = STATS + 768;
  float* D = out;                                 // d_out as scratch until final stage

  dim3 b256(256);
  prep_all_k<<<7684, b256, 0, stream>>>(conv1_w, conv2_w, qkv2_w, out2_w, qkv3_w,
                                        lsa_qkv_w, lsa_out_w,
                                        WB1, WB2, QKV2T, OUT2T, QKV3T, LSAQT, LSAOT, STATS, QSUM);

  // ---- residual block (conv output stats fused into conv epilogue) ----
  gn_stats_contig<<<1024, b256, 0, stream>>>(x, ST0);
  gn_apply_tr_k<<<16384, b256, 0, stream>>>(x, ST0, XC, 1e-6f);
  conv3x3_mfma_k<<<dim3(64, 16), b256, 0, stream>>>(XC, WB1, conv1_b, temb, g_diff, W, ST1, 1);
  gn_apply_tr_k<<<16384, b256, 0, stream>>>(W, ST1, XC, 1e-6f);
  conv3x3_mfma_k<<<dim3(64, 16), b256, 0, stream>>>(XC, WB2, nullptr, nullptr, nullptr, W, ST2, 0);
  gn_tr_resid_k<<<16384, b256, 0, stream>>>(W, x, ST2, g_res, D, 1e-6f);  // D = xf

  // ---- layer2: freq attention; out2 GEMM writes xt (W) directly ----
  for (int c = 0; c < NCHv; ++c) {
    float* XFr = D + (size_t)c * rows * 256;
    gemm_af32_k<<<dim3(6, rows / 128), b256, 0, stream>>>(XFr, 256, QKV2T, qkv2_b, QB, 768,
                                                          nullptr, 0, 0.f, nullptr, 0);
    attn2_mfma_k<<<rows / 64, b256, 0, stream>>>(QB);
    gemm_abf16_k<<<dim3(2, rows / 128), b256, 0, stream>>>(QB, 768, OUT2T,
                                                           XFr, W, (int)(c * rows),
                                                           nullptr, 256, g2, 1);
  }

  // ---- layer3: global time attention (q pooled via GEMM-fused column sums) ----
  for (int c = 0; c < NCHv; ++c) {
    const float* XTr = W + (size_t)c * rows * 256;
    gemm_af32_k<<<dim3(6, rows / 128), b256, 0, stream>>>(XTr, 256, QKV3T, qkv3_b, QB, 768,
                                                          nullptr, 0, 0.f, QSUM, (int)(c * rows));
    attn3_k<<<(rows / 256) * 8, b256, 0, stream>>>(QB, QSUM, Y3, c * (int)(rows / 256));
  }
  gemm_k<<<dim3(4, 4), b256, 0, stream>>>(Y3, 256, out3_w, 256, nullptr, Y3N, 256, 1);  // fused row-GN
  bcast_stats_k<<<512, b256, 0, stream>>>(W, Y3N, g3, ST3);   // add + layer4 GN stats fused

  // ---- layer4: LSA; out GEMM writes final output directly ----
  for (int c = 0; c < NCHv; ++c) {
    const float* XTr = W + (size_t)c * rows * 256;
    gemm_af32_k<<<dim3(6, rows / 128), b256, 0, stream>>>(XTr, 256, LSAQT, nullptr, QB, 768,
                                                          ST3, (int)(c * rows), 1e-5f, nullptr, 0);
    lsa_attn_k<<<(rows / 256) * 16, b256, 0, stream>>>(QB);
    gemm_abf16_k<<<dim3(2, rows / 128), b256, 0, stream>>>(QB, 768, LSAOT,
                                                           XTr, out, (int)(c * rows),
                                                           nullptr, 256, nullptr, 2);
  }
}

// Round 12
// 993.910 us; speedup vs baseline: 1.0375x; 1.0375x over previous
//
#include <hip/hip_runtime.h>

#define NN 16777216   // 4*256*64*256
#define CC 256
#define FF 64
#define TT 256

typedef short v8s __attribute__((ext_vector_type(8)));
typedef float v4f __attribute__((ext_vector_type(4)));

__device__ __forceinline__ unsigned short f2bf(float f) {
  unsigned u = __float_as_uint(f);
  u += 0x7fff + ((u >> 16) & 1);
  return (unsigned short)(u >> 16);
}
__device__ __forceinline__ float bf2f(unsigned short h) {
  return __uint_as_float(((unsigned)h) << 16);
}
__device__ __forceinline__ unsigned packbf2(float a, float b) {
  return (unsigned)f2bf(a) | ((unsigned)f2bf(b) << 16);
}
__device__ __forceinline__ void unpack8(uint4 u, float* d) {
  d[0] = __uint_as_float(u.x << 16); d[1] = __uint_as_float(u.x & 0xffff0000u);
  d[2] = __uint_as_float(u.y << 16); d[3] = __uint_as_float(u.y & 0xffff0000u);
  d[4] = __uint_as_float(u.z << 16); d[5] = __uint_as_float(u.z & 0xffff0000u);
  d[6] = __uint_as_float(u.w << 16); d[7] = __uint_as_float(u.w & 0xffff0000u);
}

// ---------------- helpers ----------------
__device__ __forceinline__ void blockReduce2(float& a, float& b, float* sbuf) {
  #pragma unroll
  for (int off = 32; off > 0; off >>= 1) {
    a += __shfl_down(a, off, 64);
    b += __shfl_down(b, off, 64);
  }
  int w = threadIdx.x >> 6;
  if ((threadIdx.x & 63) == 0) { sbuf[w] = a; sbuf[4 + w] = b; }
  __syncthreads();
  if (threadIdx.x == 0) {
    a = sbuf[0] + sbuf[1] + sbuf[2] + sbuf[3];
    b = sbuf[4] + sbuf[5] + sbuf[6] + sbuf[7];
  }
}

// ---------------- combined weight prep + stats zero (one dispatch) ----------------
__global__ void prep_all_k(const float* __restrict__ c1w, const float* __restrict__ c2w,
    const float* __restrict__ q2w, const float* __restrict__ o2w, const float* __restrict__ q3w,
    const float* __restrict__ lqw, const float* __restrict__ low,
    unsigned short* __restrict__ WB1, unsigned short* __restrict__ WB2,
    unsigned short* __restrict__ Q2T, unsigned short* __restrict__ O2T,
    unsigned short* __restrict__ Q3T, unsigned short* __restrict__ LQT,
    unsigned short* __restrict__ LOT, float* __restrict__ stats) {
  long s = (long)blockIdx.x * 256 + threadIdx.x;
  if (s < 1024) { stats[s] = 0.f; return; }
  s -= 1024;
  if (s < 589824) {
    int co = (int)(s / 2304), r = (int)(s % 2304);
    int ci = r / 9, tap = r % 9;
    WB1[(tap * 256 + co) * 256 + ci] = f2bf(c1w[s]);
    return;
  }
  s -= 589824;
  if (s < 589824) {
    int co = (int)(s / 2304), r = (int)(s % 2304);
    int ci = r / 9, tap = r % 9;
    WB2[(tap * 256 + co) * 256 + ci] = f2bf(c2w[s]);
    return;
  }
  s -= 589824;
  if (s < 196608) { int k = (int)(s / 768), n = (int)(s % 768); Q2T[n * 256 + k] = f2bf(q2w[s]); return; }
  s -= 196608;
  if (s < 65536)  { int k = (int)(s / 256), n = (int)(s % 256); O2T[n * 256 + k] = f2bf(o2w[s]); return; }
  s -= 65536;
  if (s < 196608) { int k = (int)(s / 768), n = (int)(s % 768); Q3T[n * 256 + k] = f2bf(q3w[s]); return; }
  s -= 196608;
  if (s < 196608) { int k = (int)(s / 768), n = (int)(s % 768); LQT[n * 256 + k] = f2bf(lqw[s]); return; }
  s -= 196608;
  if (s < 65536)  { int k = (int)(s / 256), n = (int)(s % 256); LOT[n * 256 + k] = f2bf(low[s]); return; }
}

// ---------------- GroupNorm stats (NCHW contiguous: 131072/group) ----------------
__global__ __launch_bounds__(256) void gn_stats_contig(const float* __restrict__ src, float* __restrict__ stats) {
  __shared__ float sbuf[8];
  int grp = blockIdx.x >> 3, chunk = blockIdx.x & 7;
  const float4* p = (const float4*)src + grp * 32768 + chunk * 4096;
  float s = 0.f, ss = 0.f;
  for (int i = threadIdx.x; i < 4096; i += 256) {
    float4 v = p[i];
    s += v.x + v.y + v.z + v.w;
    ss += v.x * v.x + v.y * v.y + v.z * v.z + v.w * v.w;
  }
  blockReduce2(s, ss, sbuf);
  if (threadIdx.x == 0) { atomicAdd(&stats[grp], s); atomicAdd(&stats[128 + grp], ss); }
}

// GN apply + transpose to bf16 [b][f][t][ci]
__global__ __launch_bounds__(256) void gn_apply_tr_k(const float* __restrict__ src,
    const float* __restrict__ stats, unsigned short* __restrict__ XC, float eps) {
  __shared__ float sT[32][33];
  int bx = blockIdx.x;
  int r = bx >> 6;
  int c0 = ((bx >> 3) & 7) * 32;
  int t0 = (bx & 7) * 32;
  int b = r >> 6, f = r & 63;
  int tl = threadIdx.x & 31, tr = threadIdx.x >> 5;
  #pragma unroll
  for (int i = 0; i < 4; ++i) {
    int c = c0 + tr + i * 8;
    int grp = b * 32 + (c >> 3);
    float mean = stats[grp] * (1.f / 131072.f);
    float var = stats[128 + grp] * (1.f / 131072.f) - mean * mean;
    float rv = rsqrtf(var + eps);
    float v = src[((b * 256 + c) * 64 + f) * 256 + t0 + tl];
    sT[tr + i * 8][tl] = (v - mean) * rv;
  }
  __syncthreads();
  #pragma unroll
  for (int i = 0; i < 4; ++i) {
    int t = t0 + tr + i * 8;
    XC[(((size_t)(b * 64 + f)) * 256 + t) * 256 + c0 + tl] = f2bf(sT[tl][tr + i * 8]);
  }
}

// GN apply + gated residual + transpose to XF fp32 [(b*256+t)*64+f][c]
__global__ __launch_bounds__(256) void gn_tr_resid_k(const float* __restrict__ h,
    const float* __restrict__ x, const float* __restrict__ stats,
    const float* __restrict__ gate, float* __restrict__ XF, float eps) {
  __shared__ float sT[32][33];
  int bx = blockIdx.x;
  int r = bx >> 6;
  int c0 = ((bx >> 3) & 7) * 32;
  int t0 = (bx & 7) * 32;
  int b = r >> 6, f = r & 63;
  int tl = threadIdx.x & 31, tr = threadIdx.x >> 5;
  float g = gate[0];
  #pragma unroll
  for (int i = 0; i < 4; ++i) {
    int c = c0 + tr + i * 8;
    int grp = b * 32 + (c >> 3);
    float mean = stats[grp] * (1.f / 131072.f);
    float var = stats[128 + grp] * (1.f / 131072.f) - mean * mean;
    float rv = rsqrtf(var + eps);
    int idx = ((b * 256 + c) * 64 + f) * 256 + t0 + tl;
    sT[tr + i * 8][tl] = x[idx] + g * (h[idx] - mean) * rv;
  }
  __syncthreads();
  #pragma unroll
  for (int i = 0; i < 4; ++i) {
    int t = t0 + tr + i * 8;
    XF[(((size_t)(b * 256 + t)) * 64 + f) * 256 + c0 + tl] = sT[tl][tr + i * 8];
  }
}

// ---------------- conv 3x3 via MFMA; fused output GN-stats ----------------
// XC bf16 [b][f][t][ci]; wb bf16 [tap][co][ci]; out fp32 [b][co][f][t].
// co split 4-ways (64 co/block): grid (64,16)=1024 blocks -> 4 blocks/CU.
__global__ __launch_bounds__(256, 4) void conv3x3_mfma_k(const unsigned short* __restrict__ XC,
    const unsigned short* __restrict__ wb, const float* __restrict__ bias,
    const float* __restrict__ temb, const float* __restrict__ gd,
    float* __restrict__ out, float* __restrict__ ostats, int mode) {
  __shared__ __align__(16) unsigned short sIn[258][40];
  __shared__ __align__(16) unsigned short sW[3][64][40];
  int f  = blockIdx.x;
  int b  = blockIdx.y >> 2;
  int co0 = (blockIdx.y & 3) * 64;
  int tid = threadIdx.x;
  int wave = tid >> 6, lane = tid & 63;
  int lm = lane & 15, quad = lane >> 4;
  int w64 = wave * 64;
  v4f acc[4][4];
  #pragma unroll
  for (int i = 0; i < 4; ++i)
    #pragma unroll
    for (int j = 0; j < 4; ++j) acc[i][j] = (v4f)(0.f);

  for (int ci0 = 0; ci0 < 256; ci0 += 32) {
    for (int df = 0; df < 3; ++df) {
      __syncthreads();
      // stage one input f-row (258 t x 32 ci)
      for (int s = tid; s < 1032; s += 256) {
        int tl = s >> 2, part = s & 3;
        int fi = f + df - 1, tg = tl - 1;
        uint4 val = make_uint4(0, 0, 0, 0);
        if (fi >= 0 && fi < 64 && tg >= 0 && tg < 256)
          val = *(const uint4*)&XC[(((size_t)(b * 64 + fi)) * 256 + tg) * 256 + ci0 + part * 8];
        *(uint4*)&sIn[tl][part * 8] = val;
      }
      // stage 3 taps of weights (64 co x 32 ci each)
      for (int s = tid; s < 768; s += 256) {
        int tap3 = s >> 8, r = s & 255;
        int co = r >> 2, part = r & 3;
        *(uint4*)&sW[tap3][co][part * 8] =
            *(const uint4*)&wb[((size_t)((df * 3 + tap3) * 256) + co0 + co) * 256 + ci0 + part * 8];
      }
      __syncthreads();
      #pragma unroll
      for (int dt = 0; dt < 3; ++dt) {
        v8s A[4];
        #pragma unroll
        for (int mt = 0; mt < 4; ++mt)
          A[mt] = *(const v8s*)&sIn[w64 + mt * 16 + lm + dt][quad * 8];
        #pragma unroll
        for (int nt = 0; nt < 4; ++nt) {
          v8s B = *(const v8s*)&sW[dt][nt * 16 + lm][quad * 8];
          #pragma unroll
          for (int mt = 0; mt < 4; ++mt)
            acc[mt][nt] = __builtin_amdgcn_mfma_f32_16x16x32_bf16(A[mt], B, acc[mt][nt], 0, 0, 0);
        }
      }
    }
  }
  __syncthreads();   // done reading sIn/sW; reuse sIn as float scratch
  float* sStat = (float*)sIn;     // [wave][nt][lm][2] = 512 floats
  float gdv = mode ? gd[0] : 0.f;
  float sch, qch;
  #pragma unroll
  for (int nt = 0; nt < 4; ++nt) {
    int co = co0 + nt * 16 + lm;
    float bb = 0.f;
    if (mode) bb = bias[co] + gdv * temb[b * 256 + co];
    sch = 0.f; qch = 0.f;
    #pragma unroll
    for (int mt = 0; mt < 4; ++mt) {
      int t = w64 + mt * 16 + quad * 4;
      float v0 = acc[mt][nt][0] + bb, v1 = acc[mt][nt][1] + bb;
      float v2 = acc[mt][nt][2] + bb, v3 = acc[mt][nt][3] + bb;
      if (mode) {
        v0 = v0 / (1.f + expf(-v0)); v1 = v1 / (1.f + expf(-v1));
        v2 = v2 / (1.f + expf(-v2)); v3 = v3 / (1.f + expf(-v3));
      }
      float4 o; o.x = v0; o.y = v1; o.z = v2; o.w = v3;
      *(float4*)&out[(((size_t)b * 256 + co) * 64 + f) * 256 + t] = o;
      sch += v0 + v1 + v2 + v3;
      qch += v0 * v0 + v1 * v1 + v2 * v2 + v3 * v3;
    }
    // reduce across quads (same channel, different t)
    sch += __shfl_xor(sch, 16); qch += __shfl_xor(qch, 16);
    sch += __shfl_xor(sch, 32); qch += __shfl_xor(qch, 32);
    if (quad == 0) {
      sStat[((wave * 4 + nt) * 16 + lm) * 2]     = sch;
      sStat[((wave * 4 + nt) * 16 + lm) * 2 + 1] = qch;
    }
  }
  __syncthreads();
  if (tid < 64) {
    int c = tid;                     // channel within block = nt*16+lm
    int nt = c >> 4, lmm = c & 15;
    float s = 0.f, q = 0.f;
    #pragma unroll
    for (int w = 0; w < 4; ++w) {
      s += sStat[((w * 4 + nt) * 16 + lmm) * 2];
      q += sStat[((w * 4 + nt) * 16 + lmm) * 2 + 1];
    }
    s += __shfl_xor(s, 1); q += __shfl_xor(q, 1);
    s += __shfl_xor(s, 2); q += __shfl_xor(q, 2);
    s += __shfl_xor(s, 4); q += __shfl_xor(q, 4);
    if ((c & 7) == 0) {
      int g = (co0 + c) >> 3;
      atomicAdd(&ostats[b * 32 + g], s);
      atomicAdd(&ostats[128 + b * 32 + g], q);
    }
  }
}

// ---------------- MFMA GEMM: Cb bf16 [M,N] = gn?(A fp32 [M,256]) @ B (+bias) ----------------
// 128-wide N tile (acc[4][4]): r10-proven form. Do NOT add epilogue branches:
// r11's qsum variant reshaped codegen and cost ~15us/dispatch across all call
// sites (MfmaUtil 15%->7.6%).
__global__ __launch_bounds__(256) void gemm_af32_k(const float* __restrict__ A, int lda,
    const unsigned short* __restrict__ BT, const float* __restrict__ bias,
    unsigned short* __restrict__ Cb, int ldc,
    const float* __restrict__ gstats, int growbase, float eps) {
  __shared__ __align__(16) unsigned short sA[128][40];
  __shared__ __align__(16) unsigned short sB[128][40];
  int n0 = blockIdx.x * 128, m0 = blockIdx.y * 128;
  int tid = threadIdx.x;
  int wave = tid >> 6, lane = tid & 63;
  int wm = wave >> 1, wn = wave & 1;
  int lm = lane & 15, quad = lane >> 4;
  v4f acc[4][4];
  #pragma unroll
  for (int i = 0; i < 4; ++i)
    #pragma unroll
    for (int j = 0; j < 4; ++j) acc[i][j] = (v4f)(0.f);

  for (int k0 = 0; k0 < 256; k0 += 32) {
    __syncthreads();
    #pragma unroll
    for (int i = 0; i < 4; ++i) {
      int s = tid + i * 256;
      int row = s >> 3, k4 = s & 7;
      float4 av = *(const float4*)&A[(size_t)(m0 + row) * lda + k0 + k4 * 4];
      if (gstats) {
        int grp = ((growbase + m0 + row) >> 14) * 32 + ((k0 + k4 * 4) >> 3);
        float mean = gstats[grp] * (1.f / 131072.f);
        float var = gstats[128 + grp] * (1.f / 131072.f) - mean * mean;
        float rr = rsqrtf(var + eps);
        av.x = (av.x - mean) * rr; av.y = (av.y - mean) * rr;
        av.z = (av.z - mean) * rr; av.w = (av.w - mean) * rr;
      }
      *(uint2*)&sA[row][k4 * 4] = make_uint2(packbf2(av.x, av.y), packbf2(av.z, av.w));
    }
    #pragma unroll
    for (int i = 0; i < 2; ++i) {
      int s = tid + i * 256;
      int n = s >> 2, part = s & 3;
      *(uint4*)&sB[n][part * 8] = *(const uint4*)&BT[(size_t)(n0 + n) * 256 + k0 + part * 8];
    }
    __syncthreads();
    v8s Af[4];
    #pragma unroll
    for (int mt = 0; mt < 4; ++mt)
      Af[mt] = *(const v8s*)&sA[wm * 64 + mt * 16 + lm][quad * 8];
    #pragma unroll
    for (int nt = 0; nt < 4; ++nt) {
      v8s Bf = *(const v8s*)&sB[wn * 64 + nt * 16 + lm][quad * 8];
      #pragma unroll
      for (int mt = 0; mt < 4; ++mt)
        acc[mt][nt] = __builtin_amdgcn_mfma_f32_16x16x32_bf16(Af[mt], Bf, acc[mt][nt], 0, 0, 0);
    }
  }
  #pragma unroll
  for (int nt = 0; nt < 4; ++nt) {
    int col = n0 + wn * 64 + nt * 16 + lm;
    float bb = bias ? bias[col] : 0.f;
    #pragma unroll
    for (int mt = 0; mt < 4; ++mt) {
      int row = m0 + wm * 64 + mt * 16 + quad * 4;
      #pragma unroll
      for (int r = 0; r < 4; ++r)
        Cb[(size_t)(row + r) * ldc + col] = f2bf(acc[mt][nt][r] + bb);
    }
  }
}

// ---------------- MFMA GEMM, A bf16 ----------------
// mode 0: plain bf16 Cb out.
// mode 1: fused rowGN + gate + residual-add, written TRANSPOSED into xt layout.
// mode 2: LSA direct-out: writes final out[((b*256+col)*64+f)*256+t].
__global__ __launch_bounds__(256) void gemm_abf16_k(const unsigned short* __restrict__ A, int lda,
    const unsigned short* __restrict__ BT,
    const float* __restrict__ xfin, float* __restrict__ xtout, int rowbase,
    unsigned short* __restrict__ Cb, int ldc, const float* __restrict__ gate, int mode) {
  __shared__ __align__(16) unsigned short sA[128][40];
  __shared__ __align__(16) unsigned short sB[128][40];
  int n0 = blockIdx.x * 128, m0 = blockIdx.y * 128;
  int tid = threadIdx.x;
  int wave = tid >> 6, lane = tid & 63;
  int wm = wave >> 1, wn = wave & 1;
  int lm = lane & 15, quad = lane >> 4;
  v4f acc[4][4];
  #pragma unroll
  for (int i = 0; i < 4; ++i)
    #pragma unroll
    for (int j = 0; j < 4; ++j) acc[i][j] = (v4f)(0.f);

  for (int k0 = 0; k0 < 256; k0 += 32) {
    __syncthreads();
    #pragma unroll
    for (int i = 0; i < 2; ++i) {
      int s = tid + i * 256;
      int row = s >> 2, part = s & 3;
      *(uint4*)&sA[row][part * 8] = *(const uint4*)&A[(size_t)(m0 + row) * lda + k0 + part * 8];
      *(uint4*)&sB[row][part * 8] = *(const uint4*)&BT[(size_t)(n0 + row) * 256 + k0 + part * 8];
    }
    __syncthreads();
    v8s Af[4];
    #pragma unroll
    for (int mt = 0; mt < 4; ++mt)
      Af[mt] = *(const v8s*)&sA[wm * 64 + mt * 16 + lm][quad * 8];
    #pragma unroll
    for (int nt = 0; nt < 4; ++nt) {
      v8s Bf = *(const v8s*)&sB[wn * 64 + nt * 16 + lm][quad * 8];
      #pragma unroll
      for (int mt = 0; mt < 4; ++mt)
        acc[mt][nt] = __builtin_amdgcn_mfma_f32_16x16x32_bf16(Af[mt], Bf, acc[mt][nt], 0, 0, 0);
    }
  }
  if (mode == 1) {
    float g = gate[0];
    #pragma unroll
    for (int mt = 0; mt < 4; ++mt) {
      int rowb = m0 + wm * 64 + mt * 16 + quad * 4;
      #pragma unroll
      for (int r = 0; r < 4; ++r) {
        int rowl = rowb + r;
        int rowg = rowbase + rowl;
        int b = rowg >> 14, t = (rowg >> 6) & 255, fq = rowg & 63;
        size_t xtrow = (size_t)((b * 64 + fq) * 256 + t) * 256;
        #pragma unroll
        for (int nt = 0; nt < 4; ++nt) {
          float v = acc[mt][nt][r];
          float s = v, q = v * v;
          s += __shfl_xor(s, 1); q += __shfl_xor(q, 1);
          s += __shfl_xor(s, 2); q += __shfl_xor(q, 2);
          s += __shfl_xor(s, 4); q += __shfl_xor(q, 4);
          float m = s * 0.125f;
          float var = q * 0.125f - m * m;
          float norm = (v - m) * rsqrtf(var + 1e-5f);
          int col = n0 + wn * 64 + nt * 16 + lm;
          xtout[xtrow + col] = xfin[(size_t)rowl * 256 + col] + g * norm;
        }
      }
    }
  } else if (mode == 2) {
    #pragma unroll
    for (int mt = 0; mt < 4; ++mt) {
      int rowb = m0 + wm * 64 + mt * 16 + quad * 4;
      #pragma unroll
      for (int r = 0; r < 4; ++r) {
        int rowl = rowb + r;
        int rowg = rowbase + rowl;
        int b = rowg >> 14, fq = (rowg >> 8) & 63, t = rowg & 255;
        #pragma unroll
        for (int nt = 0; nt < 4; ++nt) {
          int col = n0 + wn * 64 + nt * 16 + lm;
          float v = acc[mt][nt][r] + xfin[(size_t)rowl * 256 + col];
          xtout[(((size_t)b * 256 + col) * 64 + fq) * 256 + t] = v;
        }
      }
    }
  } else {
    #pragma unroll
    for (int nt = 0; nt < 4; ++nt) {
      int col = n0 + wn * 64 + nt * 16 + lm;
      #pragma unroll
      for (int mt = 0; mt < 4; ++mt) {
        int row = m0 + wm * 64 + mt * 16 + quad * 4;
        #pragma unroll
        for (int r = 0; r < 4; ++r)
          Cb[(size_t)(row + r) * ldc + col] = f2bf(acc[mt][nt][r]);
      }
    }
  }
}

// ---------------- fp32 GEMM (tiny out3 matmul), optional fused row-GN ----------------
__global__ __launch_bounds__(256) void gemm_k(const float* __restrict__ A, int lda,
    const float* __restrict__ Bm, int N, const float* __restrict__ bias,
    float* __restrict__ Cm, int ldc, int gn) {
  __shared__ __align__(16) float sA[16][64];
  __shared__ __align__(16) float sB[16][64];
  int n0 = blockIdx.x * 64, m0 = blockIdx.y * 64;
  int tid = threadIdx.x;
  int tx = tid & 15, ty = tid >> 4;
  int arow = m0 + (tid >> 2), acol = (tid & 3) * 4;
  int brow = tid >> 4, bcol = (tid & 15) * 4;
  float acc[4][4] = {};
  for (int k0 = 0; k0 < 256; k0 += 16) {
    __syncthreads();
    float4 av = *(const float4*)&A[(size_t)arow * lda + k0 + acol];
    sA[acol + 0][tid >> 2] = av.x;
    sA[acol + 1][tid >> 2] = av.y;
    sA[acol + 2][tid >> 2] = av.z;
    sA[acol + 3][tid >> 2] = av.w;
    *(float4*)&sB[brow][bcol] = *(const float4*)&Bm[(k0 + brow) * N + n0 + bcol];
    __syncthreads();
    #pragma unroll
    for (int kk = 0; kk < 16; ++kk) {
      float4 a = *(const float4*)&sA[kk][ty * 4];
      float4 b = *(const float4*)&sB[kk][tx * 4];
      float aa[4] = {a.x, a.y, a.z, a.w};
      float bb[4] = {b.x, b.y, b.z, b.w};
      #pragma unroll
      for (int i = 0; i < 4; ++i)
        #pragma unroll
        for (int j = 0; j < 4; ++j)
          acc[i][j] += aa[i] * bb[j];
    }
  }
  #pragma unroll
  for (int i = 0; i < 4; ++i) {
    float m = 0.f, rv = 1.f;
    if (gn) {
      float s = acc[i][0] + acc[i][1] + acc[i][2] + acc[i][3];
      float q = acc[i][0] * acc[i][0] + acc[i][1] * acc[i][1]
              + acc[i][2] * acc[i][2] + acc[i][3] * acc[i][3];
      s += __shfl_xor(s, 1); q += __shfl_xor(q, 1);
      m = s * 0.125f;
      float var = q * 0.125f - m * m;
      rv = rsqrtf(var + 1e-5f);
    }
    #pragma unroll
    for (int j = 0; j < 4; ++j) {
      int n = n0 + tx * 4 + j;
      float v = acc[i][j];
      if (gn) v = (v - m) * rv;
      else if (bias) v += bias[n];
      Cm[(size_t)(m0 + ty * 4 + i) * ldc + n] = v;
    }
  }
}

// ---------------- attention: frequency axis (seq 64) via MFMA, in-place y -> q cols ----------------
__global__ __launch_bounds__(256) void attn2_mfma_k(unsigned short* __restrict__ Q) {
  __shared__ __align__(16) unsigned short sP[4][64][72];
  __shared__ __align__(16) unsigned short sVt[4][32][72];
  int bt = blockIdx.x;
  int tid = threadIdx.x;
  int wave = tid >> 6, lane = tid & 63;
  int lm = lane & 15, quad = lane >> 4;
  const float scale = 0.17677669529663687f;
  size_t rowbase = (size_t)bt * 64;
  unsigned short (*P)[72] = sP[wave];
  unsigned short (*Vt)[72] = sVt[wave];
  #pragma unroll
  for (int hh = 0; hh < 2; ++hh) {
    int h = wave * 2 + hh;
    int hoff = h * 32;
    v8s Af[4], Bf[4];
    #pragma unroll
    for (int mt = 0; mt < 4; ++mt)
      Af[mt] = *(const v8s*)&Q[(rowbase + mt * 16 + lm) * 768 + hoff + quad * 8];
    #pragma unroll
    for (int nt = 0; nt < 4; ++nt)
      Bf[nt] = *(const v8s*)&Q[(rowbase + nt * 16 + lm) * 768 + 256 + hoff + quad * 8];
    v4f S[4][4];
    #pragma unroll
    for (int mt = 0; mt < 4; ++mt)
      #pragma unroll
      for (int nt = 0; nt < 4; ++nt)
        S[mt][nt] = __builtin_amdgcn_mfma_f32_16x16x32_bf16(Af[mt], Bf[nt], (v4f)(0.f), 0, 0, 0);
    #pragma unroll
    for (int part = 0; part < 4; ++part) {
      uint4 u = *(const uint4*)&Q[(rowbase + lane) * 768 + 512 + hoff + part * 8];
      unsigned short* up = (unsigned short*)&u;
      #pragma unroll
      for (int j = 0; j < 8; ++j) Vt[part * 8 + j][lane] = up[j];
    }
    float inv[4][4];
    #pragma unroll
    for (int mt = 0; mt < 4; ++mt) {
      #pragma unroll
      for (int r = 0; r < 4; ++r) {
        float v0 = S[mt][0][r] * scale, v1 = S[mt][1][r] * scale;
        float v2 = S[mt][2][r] * scale, v3 = S[mt][3][r] * scale;
        float mx = fmaxf(fmaxf(v0, v1), fmaxf(v2, v3));
        mx = fmaxf(mx, __shfl_xor(mx, 1));
        mx = fmaxf(mx, __shfl_xor(mx, 2));
        mx = fmaxf(mx, __shfl_xor(mx, 4));
        mx = fmaxf(mx, __shfl_xor(mx, 8));
        float e0 = __expf(v0 - mx), e1 = __expf(v1 - mx);
        float e2 = __expf(v2 - mx), e3 = __expf(v3 - mx);
        float sm = e0 + e1 + e2 + e3;
        sm += __shfl_xor(sm, 1);
        sm += __shfl_xor(sm, 2);
        sm += __shfl_xor(sm, 4);
        sm += __shfl_xor(sm, 8);
        inv[mt][r] = 1.f / sm;
        int row = mt * 16 + quad * 4 + r;
        P[row][lm]      = f2bf(e0);
        P[row][16 + lm] = f2bf(e1);
        P[row][32 + lm] = f2bf(e2);
        P[row][48 + lm] = f2bf(e3);
      }
    }
    v8s Ap[4][2], Bv[2][2];
    #pragma unroll
    for (int mt = 0; mt < 4; ++mt)
      #pragma unroll
      for (int kc = 0; kc < 2; ++kc)
        Ap[mt][kc] = *(const v8s*)&P[mt * 16 + lm][kc * 32 + quad * 8];
    #pragma unroll
    for (int nd = 0; nd < 2; ++nd)
      #pragma unroll
      for (int kc = 0; kc < 2; ++kc)
        Bv[nd][kc] = *(const v8s*)&Vt[nd * 16 + lm][kc * 32 + quad * 8];
    #pragma unroll
    for (int mt = 0; mt < 4; ++mt) {
      #pragma unroll
      for (int nd = 0; nd < 2; ++nd) {
        v4f O = (v4f)(0.f);
        O = __builtin_amdgcn_mfma_f32_16x16x32_bf16(Ap[mt][0], Bv[nd][0], O, 0, 0, 0);
        O = __builtin_amdgcn_mfma_f32_16x16x32_bf16(Ap[mt][1], Bv[nd][1], O, 0, 0, 0);
        #pragma unroll
        for (int r = 0; r < 4; ++r)
          P[mt * 16 + quad * 4 + r][nd * 16 + lm] = f2bf(O[r] * inv[mt][r]);
      }
    }
    #pragma unroll
    for (int part = 0; part < 4; ++part) {
      uint4 u = *(const uint4*)&P[lane][part * 8];
      *(uint4*)&Q[(rowbase + lane) * 768 + hoff + part * 8] = u;
    }
  }
}

// ---------------- attention: global time (pooled q, seq 256), vectorized ----------------
__global__ __launch_bounds__(256) void attn3_k(const unsigned short* __restrict__ Q3,
                                               float* __restrict__ y3, int bf_base) {
  __shared__ float sQp[64][33];
  __shared__ float sqm[32];
  __shared__ float sp[256];
  __shared__ float sred[256];
  int bfl = blockIdx.x >> 3, h = blockIdx.x & 7;
  int tid = threadIdx.x;
  int tq = tid >> 2, c4 = tid & 3;
  int d8 = c4 * 8;
  const float scale = 0.17677669529663687f;
  size_t rowbase = (size_t)bfl * 256;
  // ---- q mean over t ----
  {
    float a[8] = {};
    #pragma unroll
    for (int i = 0; i < 4; ++i) {
      int t = i * 64 + tq;
      float v[8];
      unpack8(*(const uint4*)&Q3[(rowbase + t) * 768 + h * 32 + d8], v);
      #pragma unroll
      for (int j = 0; j < 8; ++j) a[j] += v[j];
    }
    #pragma unroll
    for (int j = 0; j < 8; ++j) sQp[tq][d8 + j] = a[j];
  }
  __syncthreads();
  if (tid < 32) {
    float m = 0.f;
    for (int g = 0; g < 64; ++g) m += sQp[g][tid];
    sqm[tid] = m * (1.f / 256.f);
  }
  __syncthreads();
  // ---- k . qm ----
  {
    float dot = 0.f;
    #pragma unroll
    for (int p = 0; p < 4; ++p) {
      float v[8];
      unpack8(*(const uint4*)&Q3[(rowbase + tid) * 768 + 256 + h * 32 + p * 8], v);
      #pragma unroll
      for (int j = 0; j < 8; ++j) dot += sqm[p * 8 + j] * v[j];
    }
    sp[tid] = dot * scale;
    sred[tid] = sp[tid];
  }
  __syncthreads();
  for (int st = 128; st > 0; st >>= 1) { if (tid < st) sred[tid] = fmaxf(sred[tid], sred[tid + st]); __syncthreads(); }
  float mx = sred[0];
  __syncthreads();
  float e = expf(sp[tid] - mx);
  sred[tid] = e;
  __syncthreads();
  for (int st = 128; st > 0; st >>= 1) { if (tid < st) sred[tid] += sred[tid + st]; __syncthreads(); }
  float rinv = 1.f / sred[0];
  sp[tid] = e * rinv;
  __syncthreads();
  // ---- weighted V sum ----
  {
    float a[8] = {};
    #pragma unroll
    for (int i = 0; i < 4; ++i) {
      int t = i * 64 + tq;
      float w = sp[t];
      float v[8];
      unpack8(*(const uint4*)&Q3[(rowbase + t) * 768 + 512 + h * 32 + d8], v);
      #pragma unroll
      for (int j = 0; j < 8; ++j) a[j] += w * v[j];
    }
    #pragma unroll
    for (int j = 0; j < 8; ++j) sQp[tq][d8 + j] = a[j];
  }
  __syncthreads();
  if (tid < 32) {
    float o = 0.f;
    for (int g = 0; g < 64; ++g) o += sQp[g][tid];
    y3[(size_t)(bf_base + bfl) * 256 + h * 32 + tid] = o;
  }
}

// ---------------- LSA: local window 16 along T, bf16 in, o bf16 -> q cols ----------------
__global__ __launch_bounds__(256) void lsa_attn_k(unsigned short* __restrict__ Q4) {
  __shared__ __align__(16) float sX[16][772];
  __shared__ float sS[8][16][17];
  __shared__ float sInv[8][16];
  int bfl = blockIdx.x >> 4, w = blockIdx.x & 15;
  int tid = threadIdx.x;
  size_t rb = ((size_t)(bfl * 256 + w * 16)) * 768;
  for (int s = tid; s < 1536; s += 256) {
    int t = s / 96, c8 = (s - t * 96) * 8;
    unpack8(*(const uint4*)&Q4[rb + t * 768 + c8], &sX[t][c8]);
  }
  __syncthreads();
  const float scale = 0.17677669529663687f;
  #pragma unroll
  for (int rep = 0; rep < 8; ++rep) {
    int idx = tid + rep * 256;
    int h = idx >> 8, q = (idx >> 4) & 15, k = idx & 15;
    float dot = 0.f;
    const float* qp = &sX[q][h * 32];
    const float* kp = &sX[k][256 + h * 32];
    for (int d = 0; d < 32; ++d) dot += qp[d] * kp[d];
    sS[h][q][k] = dot * scale;
  }
  __syncthreads();
  if (tid < 128) {
    int h = tid >> 4, q = tid & 15;
    float mx = -1e30f;
    for (int k = 0; k < 16; ++k) mx = fmaxf(mx, sS[h][q][k]);
    float sum = 0.f;
    for (int k = 0; k < 16; ++k) { float e = expf(sS[h][q][k] - mx); sS[h][q][k] = e; sum += e; }
    sInv[h][q] = 1.f / sum;
  }
  __syncthreads();
  #pragma unroll
  for (int rep = 0; rep < 8; ++rep) {
    int idx = tid + rep * 256;
    int t = idx >> 7, c2 = (idx & 127) * 2;
    int h = c2 >> 5;
    float a0 = 0.f, a1 = 0.f;
    for (int k = 0; k < 16; ++k) {
      float p = sS[h][t][k];
      a0 += p * sX[k][512 + c2];
      a1 += p * sX[k][512 + c2 + 1];
    }
    float riv = sInv[h][t];
    *(unsigned*)&Q4[rb + t * 768 + c2] = packbf2(a0 * riv, a1 * riv);
  }
}

// ---------------- fused broadcast-add + layer4 GN stats ----------------
// block = half a (b,f) plane (contiguous 128KB). y3n operand is lane-constant.
// Stats of the POST-add value; proven gn_stats_xt2 reduction (32K atomics).
__global__ __launch_bounds__(256) void bcast_stats_k(float* __restrict__ XT, const float* __restrict__ y3n,
                                                     const float* __restrict__ gate, float* __restrict__ stats) {
  __shared__ float sacc[4][64];
  int bf = blockIdx.x >> 1, half = blockIdx.x & 1;
  int b = bf >> 6;
  int tid = threadIdx.x;
  float4* p = (float4*)XT + (size_t)bf * 16384 + (size_t)half * 8192;
  int lane = tid & 63, wave = tid >> 6;
  float4 a = ((const float4*)y3n)[(size_t)bf * 64 + lane];
  float g = gate[0];
  a.x *= g; a.y *= g; a.z *= g; a.w *= g;
  float s = 0.f, q = 0.f;
  #pragma unroll 4
  for (int k = 0; k < 32; ++k) {
    int idx = tid + k * 256;
    float4 v = p[idx];
    v.x += a.x; v.y += a.y; v.z += a.z; v.w += a.w;
    p[idx] = v;
    s += v.x + v.y + v.z + v.w;
    q += v.x * v.x + v.y * v.y + v.z * v.z + v.w * v.w;
  }
  s += __shfl_xor(s, 1); q += __shfl_xor(q, 1);
  if ((lane & 1) == 0) {
    int gg = (lane >> 1) & 31;
    sacc[wave][gg * 2] = s;
    sacc[wave][gg * 2 + 1] = q;
  }
  __syncthreads();
  if (tid < 64) {
    int gg = tid >> 1, isq = tid & 1;
    float acc = sacc[0][gg * 2 + isq] + sacc[1][gg * 2 + isq]
              + sacc[2][gg * 2 + isq] + sacc[3][gg * 2 + isq];
    atomicAdd(&stats[isq * 128 + b * 32 + gg], acc);
  }
}

// ---------------- launch ----------------
extern "C" void kernel_launch(void* const* d_in, const int* in_sizes, int n_in,
                              void* d_out, int out_size, void* d_ws, size_t ws_size,
                              hipStream_t stream) {
  (void)in_sizes; (void)n_in; (void)out_size;
  const float* x        = (const float*)d_in[0];
  const float* temb     = (const float*)d_in[1];
  const float* conv1_w  = (const float*)d_in[2];
  const float* conv1_b  = (const float*)d_in[3];
  const float* conv2_w  = (const float*)d_in[4];
  const float* g_diff   = (const float*)d_in[5];
  const float* g_res    = (const float*)d_in[6];
  const float* g2       = (const float*)d_in[7];
  const float* g3       = (const float*)d_in[8];
  const float* qkv2_w   = (const float*)d_in[9];
  const float* qkv2_b   = (const float*)d_in[10];
  const float* out2_w   = (const float*)d_in[11];
  const float* qkv3_w   = (const float*)d_in[12];
  const float* qkv3_b   = (const float*)d_in[13];
  const float* out3_w   = (const float*)d_in[14];
  const float* lsa_qkv_w = (const float*)d_in[15];
  const float* lsa_out_w = (const float*)d_in[16];
  float* out = (float*)d_out;
  float* ws = (float*)d_ws;

  int NCHv = 4;
  {
    auto need = [](int nch) -> size_t {
      size_t rows = 65536 / nch;
      size_t uslots = rows * 512;
      if (uslots < 8388608) uslots = 8388608;
      return 4ull * ((size_t)NN + uslots + 950272 + 198000);
    };
    if (ws_size >= need(1)) NCHv = 1;
    else if (ws_size >= need(2)) NCHv = 2;
  }
  const size_t rows = 65536 / NCHv;

  float* W = ws;                                  // NN fp32 trunk
  float* U = ws + (size_t)NN;                     // union region
  unsigned short* XC  = (unsigned short*)U;       // NN bf16 (conv staging)
  unsigned short* QB  = (unsigned short*)U;       // rows*768 bf16 (qkv)
  size_t uslots = rows * 512; if (uslots < 8388608) uslots = 8388608;
  float* WREG = U + uslots;
  unsigned short* WB1   = (unsigned short*)WREG;
  unsigned short* WB2   = WB1 + 589824;
  unsigned short* QKV2T = WB2 + 589824;
  unsigned short* OUT2T = QKV2T + 196608;
  unsigned short* QKV3T = OUT2T + 65536;
  unsigned short* LSAQT = QKV3T + 196608;
  unsigned short* LSAOT = LSAQT + 196608;
  float* Y3    = WREG + 950272;
  float* Y3O   = Y3 + 65536;
  float* Y3N   = Y3O + 65536;
  float* STATS = Y3N + 65536;                     // 1024 floats: ST0..ST3
  float* ST0 = STATS, *ST1 = STATS + 256, *ST2 = STATS + 512, *ST3 = STATS + 768;
  float* D = out;                                 // d_out as scratch until final stage

  dim3 b256(256);
  prep_all_k<<<7428, b256, 0, stream>>>(conv1_w, conv2_w, qkv2_w, out2_w, qkv3_w,
                                        lsa_qkv_w, lsa_out_w,
                                        WB1, WB2, QKV2T, OUT2T, QKV3T, LSAQT, LSAOT, STATS);

  // ---- residual block (conv output stats fused into conv epilogue) ----
  gn_stats_contig<<<1024, b256, 0, stream>>>(x, ST0);
  gn_apply_tr_k<<<16384, b256, 0, stream>>>(x, ST0, XC, 1e-6f);
  conv3x3_mfma_k<<<dim3(64, 16), b256, 0, stream>>>(XC, WB1, conv1_b, temb, g_diff, W, ST1, 1);
  gn_apply_tr_k<<<16384, b256, 0, stream>>>(W, ST1, XC, 1e-6f);
  conv3x3_mfma_k<<<dim3(64, 16), b256, 0, stream>>>(XC, WB2, nullptr, nullptr, nullptr, W, ST2, 0);
  gn_tr_resid_k<<<16384, b256, 0, stream>>>(W, x, ST2, g_res, D, 1e-6f);  // D = xf

  // ---- layer2: freq attention; out2 GEMM writes xt (W) directly ----
  for (int c = 0; c < NCHv; ++c) {
    float* XFr = D + (size_t)c * rows * 256;
    gemm_af32_k<<<dim3(6, rows / 128), b256, 0, stream>>>(XFr, 256, QKV2T, qkv2_b, QB, 768, nullptr, 0, 0.f);
    attn2_mfma_k<<<rows / 64, b256, 0, stream>>>(QB);
    gemm_abf16_k<<<dim3(2, rows / 128), b256, 0, stream>>>(QB, 768, OUT2T,
                                                           XFr, W, (int)(c * rows),
                                                           nullptr, 256, g2, 1);
  }

  // ---- layer3: global time attention (W = xt, written by layer2 epilogue) ----
  for (int c = 0; c < NCHv; ++c) {
    const float* XTr = W + (size_t)c * rows * 256;
    gemm_af32_k<<<dim3(6, rows / 128), b256, 0, stream>>>(XTr, 256, QKV3T, qkv3_b, QB, 768, nullptr, 0, 0.f);
    attn3_k<<<(rows / 256) * 8, b256, 0, stream>>>(QB, Y3, c * (int)(rows / 256));
  }
  gemm_k<<<dim3(4, 4), b256, 0, stream>>>(Y3, 256, out3_w, 256, nullptr, Y3N, 256, 1);  // fused row-GN
  bcast_stats_k<<<512, b256, 0, stream>>>(W, Y3N, g3, ST3);   // add + layer4 GN stats fused

  // ---- layer4: LSA; out GEMM writes final output directly ----
  for (int c = 0; c < NCHv; ++c) {
    const float* XTr = W + (size_t)c * rows * 256;
    gemm_af32_k<<<dim3(6, rows / 128), b256, 0, stream>>>(XTr, 256, LSAQT, nullptr, QB, 768,
                                                          ST3, (int)(c * rows), 1e-5f);
    lsa_attn_k<<<(rows / 256) * 16, b256, 0, stream>>>(QB);
    gemm_abf16_k<<<dim3(2, rows / 128), b256, 0, stream>>>(QB, 768, LSAOT,
                                                           XTr, out, (int)(c * rows),
                                                           nullptr, 256, nullptr, 2);
  }
}